// Round 13
// baseline (643.851 us; speedup 1.0000x reference)
//
#include <hip/hip_runtime.h>
#include <hip/hip_bf16.h>

#define NS 16384   // batch
#define H 256      // hidden
#define TH 768     // 3H
#define PRED 24    // decode steps
#define LDA 272    // LDS h-tile row stride (shorts); R3-R12-verified
#define WS_NEEDED (425984)

typedef short bf16x8 __attribute__((ext_vector_type(8)));
typedef float floatx4 __attribute__((ext_vector_type(4)));

__device__ __forceinline__ float b2f(unsigned short u) {
    return __uint_as_float(((unsigned int)u) << 16);
}
__device__ __forceinline__ unsigned short f2b(float f) {   // RTN-even bf16
    unsigned int u = __float_as_uint(f);
    return (unsigned short)((u + 0x7FFFu + ((u >> 16) & 1u)) >> 16);
}
__device__ __forceinline__ float fsig(float v) {
    return __builtin_amdgcn_rcpf(1.0f + __expf(-v));
}
__device__ __forceinline__ float ftanh(float v) {
    return 1.0f - 2.0f * __builtin_amdgcn_rcpf(1.0f + __expf(2.0f * v));
}

// ================= prep 1: rank-1 input-proj collapse + small vectors =================
__global__ void prep_proj(const void* __restrict__ WihP, const void* __restrict__ wprojP,
                          const void* __restrict__ bprojP, const void* __restrict__ bihP,
                          const void* __restrict__ bhhP, const void* __restrict__ woutP,
                          const void* __restrict__ boutP,
                          float* __restrict__ u, float* __restrict__ c,
                          float* __restrict__ bhn, float* __restrict__ wo,
                          float* __restrict__ b0) {
    const int j = blockIdx.x;        // 768
    const int lane = threadIdx.x;    // 64
    unsigned long long bm = __ballot(!(fabsf(b2f(((const unsigned short*)WihP)[lane])) <= 0.25f));
    const bool f32in = (bm != 0ull);

    float su = 0.f, sc = 0.f;
    if (f32in) {
        const float* row = (const float*)WihP + (size_t)j * H;
        const float* wp = (const float*)wprojP;
        const float* bp = (const float*)bprojP;
        for (int k = lane; k < H; k += 64) {
            float w = row[k];
            su = fmaf(w, wp[k], su); sc = fmaf(w, bp[k], sc);
        }
    } else {
        const unsigned short* row = (const unsigned short*)WihP + (size_t)j * H;
        const unsigned short* wp = (const unsigned short*)wprojP;
        const unsigned short* bp = (const unsigned short*)bprojP;
        for (int k = lane; k < H; k += 64) {
            float w = b2f(row[k]);
            su = fmaf(w, b2f(wp[k]), su); sc = fmaf(w, b2f(bp[k]), sc);
        }
    }
    for (int m = 32; m; m >>= 1) { su += __shfl_xor(su, m, 64); sc += __shfl_xor(sc, m, 64); }

    if (lane == 0) {
        float bih = f32in ? ((const float*)bihP)[j] : b2f(((const unsigned short*)bihP)[j]);
        float bhh = f32in ? ((const float*)bhhP)[j] : b2f(((const unsigned short*)bhhP)[j]);
        u[j] = su;
        c[j] = sc + bih + (j < 512 ? bhh : 0.f);
        if (j >= 512) bhn[j - 512] = bhh;
    }
    if (j < H && lane == 1)
        wo[j] = f32in ? ((const float*)woutP)[j] : b2f(((const unsigned short*)woutP)[j]);
    if (j == 0 && lane == 2)
        b0[0] = f32in ? ((const float*)boutP)[0] : b2f(((const unsigned short*)boutP)[0]);
}

// ======== prep 2: swizzle W_hh into MFMA-frag-contiguous bf16, 8-wave map (R9-R12) ======
// frag fi = ((w*8 + kk)*3 + g)*2 + s ; within frag: lane*8 shorts.
__global__ void prep_swz2(const void* __restrict__ WhhP, unsigned short* __restrict__ Wp) {
    const int cidx = blockIdx.x * 256 + threadIdx.x;   // 24576 chunks of 8 shorts
    unsigned long long bm = __ballot(!(fabsf(b2f(((const unsigned short*)WhhP)[threadIdx.x & 63])) <= 0.25f));
    const bool f32in = (bm != 0ull);

    const int lane = cidx & 63;
    const int fi   = cidx >> 6;         // 384 frags
    const int s    = fi & 1;
    const int g    = (fi >> 1) % 3;
    const int kk   = ((fi >> 1) / 3) & 7;
    const int w    = (fi >> 1) / 24;
    const size_t src = (size_t)(g * 256 + s * 128 + w * 16 + (lane & 15)) * H
                     + kk * 32 + (lane >> 4) * 8;
    unsigned short* dst = Wp + (size_t)cidx * 8;
    if (f32in) {
        const float* sp = (const float*)WhhP + src;
#pragma unroll
        for (int e = 0; e < 8; ++e) dst[e] = f2b(sp[e]);
    } else {
        const unsigned short* sp = (const unsigned short*)WhhP + src;
#pragma unroll
        for (int e = 0; e < 8; ++e) dst[e] = sp[e];
    }
}

// ============ prep 3: w_out as an augmented MFMA B-column (n=0) — R10/R12-verified ======
// wf[kk*512 + lane*8 + e] = (lane&15)==0 ? bf16(wo[kk*32 + (lane>>4)*8 + e]) : 0
__global__ void prep_wof(const float* __restrict__ wo, unsigned short* __restrict__ wf) {
    const int idx = blockIdx.x * 256 + threadIdx.x;   // 4096
    const int kk   = idx >> 9;
    const int lane = (idx >> 3) & 63;
    const int e    = idx & 7;
    unsigned short v = 0;
    if ((lane & 15) == 0) v = f2b(wo[kk * 32 + (lane >> 4) * 8 + e]);
    wf[idx] = v;
}

// ====== fused 24-step decode: ONE round, 64-row blocks, FULL W in registers ======
// 256 blocks x 512 thr (8 waves) = exactly 1 block/CU, 24 serial steps (not 48).
// Per wave: whole W slice bW[8][3][2] (192 regs) + wo frags (32) + acc 96 + woacc 16
// + fp32 hold (32) ~ 420 regs < 512/wave cap at 2 waves/SIMD (m69 pool 2048/SIMD).
// Double-buffered As + ONE barrier/step (R12) + MFMA-fused pred (R10/R12).
// Col map jj(s) = s*128 + 16w + lo (R9/R11/R12-verified).
__global__ __launch_bounds__(512, 1)
void decode_wf(const void* __restrict__ encP, const void* __restrict__ WihP,
               const unsigned short* __restrict__ Wp, const unsigned short* __restrict__ wf,
               const float* __restrict__ u, const float* __restrict__ c,
               const float* __restrict__ bhnA, const float* __restrict__ b0A,
               void* __restrict__ outP) {
    __shared__ __align__(16) unsigned short As[2][64 * LDA];  // 69.6 KB double-buffered h
    __shared__ float pred_out[64][PRED];                      // 6 KB
    __shared__ int sflag;

    const int tid  = threadIdx.x;
    const int w    = tid >> 6;     // 0..7
    const int lane = tid & 63;
    const int lo   = lane & 15;
    const int quad = lane >> 4;
    const int m0   = blockIdx.x * 64;

    if (tid == 0) sflag = 0;
    __syncthreads();
    if (!(fabsf(b2f(((const unsigned short*)WihP)[tid])) <= 0.25f)) sflag = 1;
    __syncthreads();
    const bool f32in = (sflag != 0);

    const float*          encF = (const float*)encP;
    const unsigned short* encB = (const unsigned short*)encP;

    // stage h0 tile (bf16) into buffer 0
    for (int i = tid; i < 64 * H; i += 512) {
        int r = i >> 8, col = i & 255;
        float hv = f32in ? encF[(size_t)(m0 + r) * H + col] : b2f(encB[(size_t)(m0 + r) * H + col]);
        As[0][r * LDA + col] = f2b(hv);
    }

    // per-lane gate constants, jj(s) = s*128 + 16w + lo
    float ur[2], uz[2], un[2], cr[2], cz[2], cn[2], bh[2];
#pragma unroll
    for (int s = 0; s < 2; ++s) {
        const int jj = s * 128 + w * 16 + lo;
        ur[s] = u[jj];       uz[s] = u[256 + jj];       un[s] = u[512 + jj];
        cr[s] = c[jj];       cz[s] = c[256 + jj];       cn[s] = c[512 + jj];
        bh[s] = bhnA[jj];
    }
    const float b0 = b0A[0];

    // fp32 h carried in registers (R4-verified): lane owns (row=im*16+quad*4+v, col=jj(s))
    float hold[4][4][2];
#pragma unroll
    for (int im = 0; im < 4; ++im)
#pragma unroll
        for (int v = 0; v < 4; ++v)
#pragma unroll
            for (int s = 0; s < 2; ++s) {
                int row = m0 + im * 16 + quad * 4 + v;
                int jj  = s * 128 + w * 16 + lo;
                hold[im][v][s] = f32in ? encF[(size_t)row * H + jj]
                                       : b2f(encB[(size_t)row * H + jj]);
            }

    // ---- one-time FULL W residency load: 48 frags = 192 regs + 8 wo frags = 32 regs ----
    const unsigned short* wp = Wp + (size_t)w * 24576 + lane * 8;  // + frag*512
    bf16x8 bW[8][3][2];
#pragma unroll
    for (int kk = 0; kk < 8; ++kk)
#pragma unroll
        for (int g = 0; g < 3; ++g)
#pragma unroll
            for (int s = 0; s < 2; ++s)
                bW[kk][g][s] = *(const bf16x8*)(wp + (size_t)((kk * 3 + g) * 2 + s) * 512);
    bf16x8 bWo[8];
#pragma unroll
    for (int kk = 0; kk < 8; ++kk)
        bWo[kk] = *(const bf16x8*)(wf + kk * 512 + lane * 8);

    __syncthreads();   // h0 visible

    int p = 0;
#pragma unroll 1
    for (int t = 0; t < PRED; ++t) {
        floatx4 acc[3][2][4];   // [g][s][im]
        floatx4 woacc[4];       // pred(t-1), col 0 valid
#pragma unroll
        for (int g = 0; g < 3; ++g)
#pragma unroll
            for (int s = 0; s < 2; ++s)
#pragma unroll
                for (int im = 0; im < 4; ++im) acc[g][s][im] = (floatx4){0.f, 0.f, 0.f, 0.f};
#pragma unroll
        for (int im = 0; im < 4; ++im) woacc[im] = (floatx4){0.f, 0.f, 0.f, 0.f};

        const unsigned short* Ap = As[p];
        unsigned short*       An = As[p ^ 1];

        // ---- K-loop: zero global + zero W-LDS traffic; 28 MFMAs per kk ----
#pragma unroll
        for (int kk = 0; kk < 8; ++kk) {
            bf16x8 a[4];
#pragma unroll
            for (int im = 0; im < 4; ++im)
                a[im] = *(const bf16x8*)&Ap[(im * 16 + lo) * LDA + kk * 32 + quad * 8];
#pragma unroll
            for (int g = 0; g < 3; ++g)
#pragma unroll
                for (int s = 0; s < 2; ++s)
#pragma unroll
                    for (int im = 0; im < 4; ++im)
                        acc[g][s][im] = __builtin_amdgcn_mfma_f32_16x16x32_bf16(
                            a[im], bW[kk][g][s], acc[g][s][im], 0, 0, 0);
#pragma unroll
            for (int im = 0; im < 4; ++im)
                woacc[im] = __builtin_amdgcn_mfma_f32_16x16x32_bf16(a[im], bWo[kk], woacc[im], 0, 0, 0);
        }

        // ---- epilogue: no barrier before it (reads Ap regs/hold, writes An) ----
#pragma unroll
        for (int im = 0; im < 4; ++im) {
#pragma unroll
            for (int v = 0; v < 4; ++v) {
                const int row = im * 16 + quad * 4 + v;
                float xv = 0.f;
                if (t > 0) xv = b0 + __shfl(woacc[im][v], quad << 4, 64);
#pragma unroll
                for (int s = 0; s < 2; ++s) {
                    const int jj = s * 128 + w * 16 + lo;
                    float r  = fsig(fmaf(xv, ur[s], cr[s]) + acc[0][s][im][v]);
                    float z  = fsig(fmaf(xv, uz[s], cz[s]) + acc[1][s][im][v]);
                    float n  = ftanh(fmaf(xv, un[s], cn[s]) + r * (acc[2][s][im][v] + bh[s]));
                    float hn = fmaf(z, hold[im][v][s] - n, n);   // (1-z)*n + z*h
                    hold[im][v][s] = hn;
                    An[row * LDA + jj] = f2b(hn);
                }
                if (w == 0 && lo == 0 && t > 0) pred_out[row][t - 1] = xv;
            }
        }
        __syncthreads();   // ONE barrier/step
        p ^= 1;
    }

    // ---- final pred(23) = h(24)·wo + b0 (wo-only MFMA pass, wave 0) ----
    if (w == 0) {
        const unsigned short* Ap = As[p];
        floatx4 wa[4];
#pragma unroll
        for (int im = 0; im < 4; ++im) wa[im] = (floatx4){0.f, 0.f, 0.f, 0.f};
#pragma unroll
        for (int kk = 0; kk < 8; ++kk) {
#pragma unroll
            for (int im = 0; im < 4; ++im) {
                bf16x8 a = *(const bf16x8*)&Ap[(im * 16 + lo) * LDA + kk * 32 + quad * 8];
                wa[im] = __builtin_amdgcn_mfma_f32_16x16x32_bf16(a, bWo[kk], wa[im], 0, 0, 0);
            }
        }
        if (lo == 0) {
#pragma unroll
            for (int im = 0; im < 4; ++im)
#pragma unroll
                for (int v = 0; v < 4; ++v)
                    pred_out[im * 16 + quad * 4 + v][PRED - 1] = b0 + wa[im][v];
        }
    }
    __syncthreads();

    // single coalesced output store
    for (int i = tid; i < 64 * PRED; i += 512) {
        int row = i / PRED, tt = i % PRED;
        float pr = pred_out[row][tt];
        if (f32in) ((float*)outP)[(size_t)(m0 + row) * PRED + tt] = pr;
        else ((unsigned short*)outP)[(size_t)(m0 + row) * PRED + tt] = f2b(pr);
    }
}

// ================= fallback (R3, proven): zero-workspace fused decode =================
__global__ __launch_bounds__(512, 2)
void decode_all(const void* __restrict__ encP,   const void* __restrict__ wprojP,
                const void* __restrict__ bprojP, const void* __restrict__ WihP,
                const void* __restrict__ bihP,   const void* __restrict__ WhhP,
                const void* __restrict__ bhhP,   const void* __restrict__ woutP,
                const void* __restrict__ boutP,  void* __restrict__ outP) {
    __shared__ __align__(16) unsigned short Asf[64 * LDA];
    __shared__ float u_lds[TH], c_lds[TH];
    __shared__ float bhn_lds[H], wo_lds[H];
    __shared__ float wp_lds[H], bp_lds[H];
    __shared__ float pred_lds[2][64];
    __shared__ int sflag;

    const int tid  = threadIdx.x;
    const int wid  = tid >> 6;
    const int lane = tid & 63;
    const int lo   = lane & 15;
    const int quad = lane >> 4;
    const int rh   = wid & 3;
    const int ch   = wid >> 2;
    const int m0   = blockIdx.x * 64;

    if (tid == 0) sflag = 0;
    __syncthreads();
    if (!(fabsf(b2f(((const unsigned short*)WihP)[tid])) <= 0.25f)) sflag = 1;
    __syncthreads();
    const bool f32in = (sflag != 0);

    const float*          encF = (const float*)encP;
    const unsigned short* encB = (const unsigned short*)encP;
    const unsigned short* WhhB = (const unsigned short*)WhhP;
    const float*          WhhF = (const float*)WhhP;

    if (tid < H) {
        wp_lds[tid] = f32in ? ((const float*)wprojP)[tid] : b2f(((const unsigned short*)wprojP)[tid]);
        bp_lds[tid] = f32in ? ((const float*)bprojP)[tid] : b2f(((const unsigned short*)bprojP)[tid]);
        wo_lds[tid] = f32in ? ((const float*)woutP)[tid]  : b2f(((const unsigned short*)woutP)[tid]);
    }
    __syncthreads();

    for (int j = tid; j < TH; j += 512) {
        float su = 0.f, sc = 0.f;
        if (f32in) {
            const float* row = (const float*)WihP + (size_t)j * H;
            for (int k = 0; k < H; ++k) { float w = row[k]; su = fmaf(w, wp_lds[k], su); sc = fmaf(w, bp_lds[k], sc); }
        } else {
            const unsigned short* row = (const unsigned short*)WihP + (size_t)j * H;
            for (int k = 0; k < H; ++k) { float w = b2f(row[k]); su = fmaf(w, wp_lds[k], su); sc = fmaf(w, bp_lds[k], sc); }
        }
        float bih = f32in ? ((const float*)bihP)[j] : b2f(((const unsigned short*)bihP)[j]);
        float bhh = f32in ? ((const float*)bhhP)[j] : b2f(((const unsigned short*)bhhP)[j]);
        u_lds[j] = su;
        c_lds[j] = sc + bih + (j < 512 ? bhh : 0.f);
        if (j >= 512) bhn_lds[j - 512] = bhh;
    }

    for (int i = tid; i < 64 * H; i += 512) {
        int r = i >> 8, col = i & 255;
        float hv = f32in ? encF[(size_t)(m0 + r) * H + col] : b2f(encB[(size_t)(m0 + r) * H + col]);
        Asf[r * LDA + col] = f2b(hv);
    }
    float hold[8][4];
#pragma unroll
    for (int s = 0; s < 8; ++s)
#pragma unroll
        for (int v = 0; v < 4; ++v) {
            int row = m0 + rh * 16 + quad * 4 + v;
            int jj  = ch * 128 + s * 16 + lo;
            hold[s][v] = f32in ? encF[(size_t)row * H + jj] : b2f(encB[(size_t)row * H + jj]);
        }
    const float b0 = f32in ? ((const float*)boutP)[0] : b2f(((const unsigned short*)boutP)[0]);

    float xm[4] = {0.f, 0.f, 0.f, 0.f};
    __syncthreads();

    const int aBase = (rh * 16 + lo) * LDA;
    const int wCol0 = ch * 128 + lo;

#pragma unroll 1
    for (int t = 0; t < PRED; ++t) {
        floatx4 acc[3][8];
#pragma unroll
        for (int g = 0; g < 3; ++g)
#pragma unroll
            for (int s = 0; s < 8; ++s) acc[g][s] = (floatx4){0.f, 0.f, 0.f, 0.f};

        if (f32in) {
#pragma unroll 1
            for (int kk = 0; kk < 8; ++kk) {
                bf16x8 a = *(const bf16x8*)&Asf[aBase + kk * 32 + quad * 8];
#pragma unroll
                for (int g = 0; g < 3; ++g)
#pragma unroll
                    for (int s = 0; s < 8; ++s) {
                        const float* wr = WhhF + (size_t)(g * 256 + wCol0 + s * 16) * H + kk * 32 + quad * 8;
                        float4 w0 = *(const float4*)wr;
                        float4 w1 = *(const float4*)(wr + 4);
                        bf16x8 b;
                        b[0] = (short)f2b(w0.x); b[1] = (short)f2b(w0.y);
                        b[2] = (short)f2b(w0.z); b[3] = (short)f2b(w0.w);
                        b[4] = (short)f2b(w1.x); b[5] = (short)f2b(w1.y);
                        b[6] = (short)f2b(w1.z); b[7] = (short)f2b(w1.w);
                        acc[g][s] = __builtin_amdgcn_mfma_f32_16x16x32_bf16(a, b, acc[g][s], 0, 0, 0);
                    }
            }
        } else {
#pragma unroll 1
            for (int kk = 0; kk < 8; ++kk) {
                bf16x8 a = *(const bf16x8*)&Asf[aBase + kk * 32 + quad * 8];
#pragma unroll
                for (int g = 0; g < 3; ++g)
#pragma unroll
                    for (int s = 0; s < 8; ++s) {
                        bf16x8 b = *(const bf16x8*)(WhhB + (size_t)(g * 256 + wCol0 + s * 16) * H + kk * 32 + quad * 8);
                        acc[g][s] = __builtin_amdgcn_mfma_f32_16x16x32_bf16(a, b, acc[g][s], 0, 0, 0);
                    }
            }
        }
        __syncthreads();

        float pp[4] = {0.f, 0.f, 0.f, 0.f};
#pragma unroll
        for (int s = 0; s < 8; ++s) {
            const int jj = ch * 128 + s * 16 + lo;
            const float urr = u_lds[jj], uzz = u_lds[256 + jj], unn = u_lds[512 + jj];
            const float crr = c_lds[jj], czz = c_lds[256 + jj], cnn = c_lds[512 + jj];
            const float bhn = bhn_lds[jj], wovv = wo_lds[jj];
#pragma unroll
            for (int v = 0; v < 4; ++v) {
                const float xv = xm[v];
                float r  = fsig(fmaf(xv, urr, crr) + acc[0][s][v]);
                float z  = fsig(fmaf(xv, uzz, czz) + acc[1][s][v]);
                float n  = ftanh(fmaf(xv, unn, cnn) + r * (acc[2][s][v] + bhn));
                float hn = fmaf(z, hold[s][v] - n, n);
                hold[s][v] = hn;
                Asf[(rh * 16 + quad * 4 + v) * LDA + jj] = f2b(hn);
                pp[v] = fmaf(hn, wovv, pp[v]);
            }
        }
#pragma unroll
        for (int v = 0; v < 4; ++v) {
            float pv = pp[v];
            pv += __shfl_xor(pv, 1, 64);
            pv += __shfl_xor(pv, 2, 64);
            pv += __shfl_xor(pv, 4, 64);
            pv += __shfl_xor(pv, 8, 64);
            if (lo == 0) pred_lds[ch][rh * 16 + quad * 4 + v] = pv;
        }
        __syncthreads();

#pragma unroll
        for (int v = 0; v < 4; ++v) {
            const int ml = rh * 16 + quad * 4 + v;
            xm[v] = b0 + pred_lds[0][ml] + pred_lds[1][ml];
        }
        if (tid < 64) {
            float pr = b0 + pred_lds[0][tid] + pred_lds[1][tid];
            if (f32in) ((float*)outP)[(size_t)(m0 + tid) * PRED + t] = pr;
            else ((unsigned short*)outP)[(size_t)(m0 + tid) * PRED + t] = f2b(pr);
        }
    }
}

extern "C" void kernel_launch(void* const* d_in, const int* in_sizes, int n_in,
                              void* d_out, int out_size, void* d_ws, size_t ws_size,
                              hipStream_t stream) {
    if (ws_size >= (size_t)WS_NEEDED) {
        char* ws = (char*)d_ws;
        unsigned short* Wp = (unsigned short*)ws;            // 393216 B
        float* u   = (float*)(ws + 393216);                  // 3072 B
        float* c   = (float*)(ws + 396288);                  // 3072 B
        float* bhn = (float*)(ws + 399360);                  // 1024 B
        float* wo  = (float*)(ws + 400384);                  // 1024 B
        float* b0  = (float*)(ws + 401408);                  // 1024 B
        unsigned short* wf = (unsigned short*)(ws + 402432); // 8192 B
        prep_proj<<<TH, 64, 0, stream>>>(d_in[3], d_in[1], d_in[2], d_in[4], d_in[6],
                                         d_in[7], d_in[8], u, c, bhn, wo, b0);
        prep_swz2<<<96, 256, 0, stream>>>(d_in[5], Wp);
        prep_wof<<<16, 256, 0, stream>>>(wo, wf);
        decode_wf<<<NS / 64, 512, 0, stream>>>(d_in[0], d_in[3], Wp, wf, u, c, bhn, b0, d_out);
    } else {
        decode_all<<<NS / 64, 512, 0, stream>>>(d_in[0], d_in[1], d_in[2], d_in[3],
                                                d_in[4], d_in[5], d_in[6], d_in[7],
                                                d_in[8], d_out);
    }
}

// Round 14
// 334.524 us; speedup vs baseline: 1.9247x; 1.9247x over previous
//
#include <hip/hip_runtime.h>
#include <hip/hip_bf16.h>

#define NS 16384   // batch
#define H 256      // hidden
#define TH 768     // 3H
#define PRED 24    // decode steps
#define LDA 272    // LDS h-tile row stride (shorts); R3-R13-verified
#define WS_NEEDED (425984)

typedef short bf16x8 __attribute__((ext_vector_type(8)));
typedef float floatx4 __attribute__((ext_vector_type(4)));

__device__ __forceinline__ float b2f(unsigned short u) {
    return __uint_as_float(((unsigned int)u) << 16);
}
__device__ __forceinline__ unsigned short f2b(float f) {   // RTN-even bf16
    unsigned int u = __float_as_uint(f);
    return (unsigned short)((u + 0x7FFFu + ((u >> 16) & 1u)) >> 16);
}
__device__ __forceinline__ float fsig(float v) {
    return __builtin_amdgcn_rcpf(1.0f + __expf(-v));
}
__device__ __forceinline__ float ftanh(float v) {
    return 1.0f - 2.0f * __builtin_amdgcn_rcpf(1.0f + __expf(2.0f * v));
}

// ================= prep 1: rank-1 input-proj collapse + small vectors =================
__global__ void prep_proj(const void* __restrict__ WihP, const void* __restrict__ wprojP,
                          const void* __restrict__ bprojP, const void* __restrict__ bihP,
                          const void* __restrict__ bhhP, const void* __restrict__ woutP,
                          const void* __restrict__ boutP,
                          float* __restrict__ u, float* __restrict__ c,
                          float* __restrict__ bhn, float* __restrict__ wo,
                          float* __restrict__ b0) {
    const int j = blockIdx.x;        // 768
    const int lane = threadIdx.x;    // 64
    unsigned long long bm = __ballot(!(fabsf(b2f(((const unsigned short*)WihP)[lane])) <= 0.25f));
    const bool f32in = (bm != 0ull);

    float su = 0.f, sc = 0.f;
    if (f32in) {
        const float* row = (const float*)WihP + (size_t)j * H;
        const float* wp = (const float*)wprojP;
        const float* bp = (const float*)bprojP;
        for (int k = lane; k < H; k += 64) {
            float w = row[k];
            su = fmaf(w, wp[k], su); sc = fmaf(w, bp[k], sc);
        }
    } else {
        const unsigned short* row = (const unsigned short*)WihP + (size_t)j * H;
        const unsigned short* wp = (const unsigned short*)wprojP;
        const unsigned short* bp = (const unsigned short*)bprojP;
        for (int k = lane; k < H; k += 64) {
            float w = b2f(row[k]);
            su = fmaf(w, b2f(wp[k]), su); sc = fmaf(w, b2f(bp[k]), sc);
        }
    }
    for (int m = 32; m; m >>= 1) { su += __shfl_xor(su, m, 64); sc += __shfl_xor(sc, m, 64); }

    if (lane == 0) {
        float bih = f32in ? ((const float*)bihP)[j] : b2f(((const unsigned short*)bihP)[j]);
        float bhh = f32in ? ((const float*)bhhP)[j] : b2f(((const unsigned short*)bhhP)[j]);
        u[j] = su;
        c[j] = sc + bih + (j < 512 ? bhh : 0.f);
        if (j >= 512) bhn[j - 512] = bhh;
    }
    if (j < H && lane == 1)
        wo[j] = f32in ? ((const float*)woutP)[j] : b2f(((const unsigned short*)woutP)[j]);
    if (j == 0 && lane == 2)
        b0[0] = f32in ? ((const float*)boutP)[0] : b2f(((const unsigned short*)boutP)[0]);
}

// ======== prep 2: swizzle W_hh into MFMA-frag-contiguous bf16, 8-wave map (R9-R12) ======
// frag fi = ((w*8 + kk)*3 + g)*2 + s ; within frag: lane*8 shorts.
__global__ void prep_swz2(const void* __restrict__ WhhP, unsigned short* __restrict__ Wp) {
    const int cidx = blockIdx.x * 256 + threadIdx.x;   // 24576 chunks of 8 shorts
    unsigned long long bm = __ballot(!(fabsf(b2f(((const unsigned short*)WhhP)[threadIdx.x & 63])) <= 0.25f));
    const bool f32in = (bm != 0ull);

    const int lane = cidx & 63;
    const int fi   = cidx >> 6;         // 384 frags
    const int s    = fi & 1;
    const int g    = (fi >> 1) % 3;
    const int kk   = ((fi >> 1) / 3) & 7;
    const int w    = (fi >> 1) / 24;
    const size_t src = (size_t)(g * 256 + s * 128 + w * 16 + (lane & 15)) * H
                     + kk * 32 + (lane >> 4) * 8;
    unsigned short* dst = Wp + (size_t)cidx * 8;
    if (f32in) {
        const float* sp = (const float*)WhhP + src;
#pragma unroll
        for (int e = 0; e < 8; ++e) dst[e] = f2b(sp[e]);
    } else {
        const unsigned short* sp = (const unsigned short*)WhhP + src;
#pragma unroll
        for (int e = 0; e < 8; ++e) dst[e] = sp[e];
    }
}

// ============ prep 3: w_out as an augmented MFMA B-column (n=0) — R10/R12-verified ======
__global__ void prep_wof(const float* __restrict__ wo, unsigned short* __restrict__ wf) {
    const int idx = blockIdx.x * 256 + threadIdx.x;   // 4096
    const int kk   = idx >> 9;
    const int lane = (idx >> 3) & 63;
    const int e    = idx & 7;
    unsigned short v = 0;
    if ((lane & 15) == 0) v = f2b(wo[kk * 32 + (lane >> 4) * 8 + e]);
    wf[idx] = v;
}

// ====== fused 24-step decode: R12 structure + fp32 h_old in registers ======
// 512 blocks x 512 thr (8 waves), 32 rows/block, 1 block/CU, 2 rounds.
// W: kk0-5 in regs (144), kk6-7 wave-private LDS (R11/R12). Double-buffered As,
// ONE barrier/step, MFMA-fused pred (R10/R12). NEW: h_old carried in 16 fp32 regs
// (removes 16 ds_read_u16 + b2f from the epilogue critical path; R4-verified pattern).
__global__ __launch_bounds__(512, 2)
void decode_wr3(const void* __restrict__ encP, const void* __restrict__ WihP,
                const unsigned short* __restrict__ Wp, const unsigned short* __restrict__ wf,
                const float* __restrict__ u, const float* __restrict__ c,
                const float* __restrict__ bhnA, const float* __restrict__ b0A,
                void* __restrict__ outP) {
    __shared__ __align__(16) unsigned short As[2][32 * LDA];  // 34.8 KB double-buffered h
    __shared__ __align__(16) unsigned short Wl[8][6144];      // 96 KB kk6-7 W, wave-private
    __shared__ __align__(16) unsigned short Wf[8 * 512];      // 8 KB wo-frags (shared)
    __shared__ float pred_out[32][PRED];                      // 3 KB
    __shared__ int sflag;

    const int tid  = threadIdx.x;
    const int w    = tid >> 6;     // 0..7
    const int lane = tid & 63;
    const int lo   = lane & 15;
    const int quad = lane >> 4;
    const int m0   = blockIdx.x * 32;

    if (tid == 0) sflag = 0;
    __syncthreads();
    if (!(fabsf(b2f(((const unsigned short*)WihP)[tid])) <= 0.25f)) sflag = 1;
    __syncthreads();
    const bool f32in = (sflag != 0);

    const float*          encF = (const float*)encP;
    const unsigned short* encB = (const unsigned short*)encP;

    // stage h0 tile (bf16) into buffer 0 + wo-frags
    for (int i = tid; i < 32 * H; i += 512) {
        int r = i >> 8, col = i & 255;
        float hv = f32in ? encF[(size_t)(m0 + r) * H + col] : b2f(encB[(size_t)(m0 + r) * H + col]);
        As[0][r * LDA + col] = f2b(hv);
    }
    for (int i = tid; i < 4096; i += 512) Wf[i] = wf[i];

    // per-lane gate constants, jj(s) = s*128 + 16w + lo (R9/R11/R12-verified)
    float ur[2], uz[2], un[2], cr[2], cz[2], cn[2], bh[2];
#pragma unroll
    for (int s = 0; s < 2; ++s) {
        const int jj = s * 128 + w * 16 + lo;
        ur[s] = u[jj];       uz[s] = u[256 + jj];       un[s] = u[512 + jj];
        cr[s] = c[jj];       cz[s] = c[256 + jj];       cn[s] = c[512 + jj];
        bh[s] = bhnA[jj];
    }
    const float b0 = b0A[0];

    // NEW: fp32 h_old in registers — lane owns (row=im*16+quad*4+v, col=jj(s))
    float hold[2][4][2];
#pragma unroll
    for (int im = 0; im < 2; ++im)
#pragma unroll
        for (int v = 0; v < 4; ++v)
#pragma unroll
            for (int s = 0; s < 2; ++s) {
                int row = m0 + im * 16 + quad * 4 + v;
                int jj  = s * 128 + w * 16 + lo;
                hold[im][v][s] = f32in ? encF[(size_t)row * H + jj]
                                       : b2f(encB[(size_t)row * H + jj]);
            }

    // ---- one-time W residency load (R11/R12-verified) ----
    const unsigned short* wp = Wp + (size_t)w * 24576 + lane * 8;  // + frag*512
    bf16x8 bW[6][3][2];                                            // kk0-5: 144 regs
#pragma unroll
    for (int kk = 0; kk < 6; ++kk)
#pragma unroll
        for (int g = 0; g < 3; ++g)
#pragma unroll
            for (int s = 0; s < 2; ++s)
                bW[kk][g][s] = *(const bf16x8*)(wp + (size_t)((kk * 3 + g) * 2 + s) * 512);
#pragma unroll
    for (int kk = 6; kk < 8; ++kk)
#pragma unroll
        for (int g = 0; g < 3; ++g)
#pragma unroll
            for (int s = 0; s < 2; ++s) {
                bf16x8 v = *(const bf16x8*)(wp + (size_t)((kk * 3 + g) * 2 + s) * 512);
                *(bf16x8*)&Wl[w][(((kk - 6) * 3 + g) * 2 + s) * 512 + lane * 8] = v;
            }
    __syncthreads();   // h0 + Wf visible

    int p = 0;
#pragma unroll 1
    for (int t = 0; t < PRED; ++t) {
        floatx4 acc[3][2][2];   // [g][s][im]
        floatx4 woacc[2];       // pred(t-1) accum, col 0 valid
#pragma unroll
        for (int g = 0; g < 3; ++g)
#pragma unroll
            for (int s = 0; s < 2; ++s)
#pragma unroll
                for (int im = 0; im < 2; ++im) acc[g][s][im] = (floatx4){0.f, 0.f, 0.f, 0.f};
        woacc[0] = (floatx4){0.f, 0.f, 0.f, 0.f};
        woacc[1] = (floatx4){0.f, 0.f, 0.f, 0.f};

        const unsigned short* Ap = As[p];
        unsigned short*       An = As[p ^ 1];

        // ---- K-loop: zero global traffic; gates + fused wo column; no barrier inside ----
#pragma unroll
        for (int kk = 0; kk < 8; ++kk) {
            bf16x8 a[2];
#pragma unroll
            for (int im = 0; im < 2; ++im)
                a[im] = *(const bf16x8*)&Ap[(im * 16 + lo) * LDA + kk * 32 + quad * 8];
            bf16x8 bwv = *(const bf16x8*)&Wf[kk * 512 + lane * 8];
            if (kk < 6) {
#pragma unroll
                for (int g = 0; g < 3; ++g)
#pragma unroll
                    for (int s = 0; s < 2; ++s)
#pragma unroll
                        for (int im = 0; im < 2; ++im)
                            acc[g][s][im] = __builtin_amdgcn_mfma_f32_16x16x32_bf16(
                                a[im], bW[kk][g][s], acc[g][s][im], 0, 0, 0);
            } else {
                bf16x8 b[3][2];
#pragma unroll
                for (int g = 0; g < 3; ++g)
#pragma unroll
                    for (int s = 0; s < 2; ++s)
                        b[g][s] = *(const bf16x8*)&Wl[w][(((kk - 6) * 3 + g) * 2 + s) * 512 + lane * 8];
#pragma unroll
                for (int g = 0; g < 3; ++g)
#pragma unroll
                    for (int s = 0; s < 2; ++s)
#pragma unroll
                        for (int im = 0; im < 2; ++im)
                            acc[g][s][im] = __builtin_amdgcn_mfma_f32_16x16x32_bf16(
                                a[im], b[g][s], acc[g][s][im], 0, 0, 0);
            }
#pragma unroll
            for (int im = 0; im < 2; ++im)
                woacc[im] = __builtin_amdgcn_mfma_f32_16x16x32_bf16(a[im], bwv, woacc[im], 0, 0, 0);
        }

        // ---- epilogue: h_old from registers; reads Ap (A-frags only), writes An ----
#pragma unroll
        for (int im = 0; im < 2; ++im) {
#pragma unroll
            for (int v = 0; v < 4; ++v) {
                const int row = im * 16 + quad * 4 + v;
                float xv = 0.f;
                if (t > 0) xv = b0 + __shfl(woacc[im][v], quad << 4, 64);
#pragma unroll
                for (int s = 0; s < 2; ++s) {
                    const int jj = s * 128 + w * 16 + lo;
                    float r  = fsig(fmaf(xv, ur[s], cr[s]) + acc[0][s][im][v]);
                    float z  = fsig(fmaf(xv, uz[s], cz[s]) + acc[1][s][im][v]);
                    float n  = ftanh(fmaf(xv, un[s], cn[s]) + r * (acc[2][s][im][v] + bh[s]));
                    float hn = fmaf(z, hold[im][v][s] - n, n);   // (1-z)*n + z*h
                    hold[im][v][s] = hn;
                    An[row * LDA + jj] = f2b(hn);
                }
                if (w == 0 && lo == 0 && t > 0) pred_out[row][t - 1] = xv;
            }
        }
        __syncthreads();   // ONE barrier/step: h(t+1) complete, Ap reads done
        p ^= 1;
    }

    // ---- final pred(23) = h(24)·wo + b0 (wo-only MFMA pass, wave 0) ----
    if (w == 0) {
        const unsigned short* Ap = As[p];
        floatx4 wa[2];
        wa[0] = (floatx4){0.f, 0.f, 0.f, 0.f};
        wa[1] = (floatx4){0.f, 0.f, 0.f, 0.f};
#pragma unroll
        for (int kk = 0; kk < 8; ++kk) {
            bf16x8 bwv = *(const bf16x8*)&Wf[kk * 512 + lane * 8];
#pragma unroll
            for (int im = 0; im < 2; ++im) {
                bf16x8 a = *(const bf16x8*)&Ap[(im * 16 + lo) * LDA + kk * 32 + quad * 8];
                wa[im] = __builtin_amdgcn_mfma_f32_16x16x32_bf16(a, bwv, wa[im], 0, 0, 0);
            }
        }
        if (lo == 0) {
#pragma unroll
            for (int im = 0; im < 2; ++im)
#pragma unroll
                for (int v = 0; v < 4; ++v)
                    pred_out[im * 16 + quad * 4 + v][PRED - 1] = b0 + wa[im][v];
        }
    }
    __syncthreads();

    // single coalesced output store
    for (int i = tid; i < 32 * PRED; i += 512) {
        int row = i / PRED, tt = i % PRED;
        float pr = pred_out[row][tt];
        if (f32in) ((float*)outP)[(size_t)(m0 + row) * PRED + tt] = pr;
        else ((unsigned short*)outP)[(size_t)(m0 + row) * PRED + tt] = f2b(pr);
    }
}

// ================= fallback (R3, proven): zero-workspace fused decode =================
__global__ __launch_bounds__(512, 2)
void decode_all(const void* __restrict__ encP,   const void* __restrict__ wprojP,
                const void* __restrict__ bprojP, const void* __restrict__ WihP,
                const void* __restrict__ bihP,   const void* __restrict__ WhhP,
                const void* __restrict__ bhhP,   const void* __restrict__ woutP,
                const void* __restrict__ boutP,  void* __restrict__ outP) {
    __shared__ __align__(16) unsigned short Asf[64 * LDA];
    __shared__ float u_lds[TH], c_lds[TH];
    __shared__ float bhn_lds[H], wo_lds[H];
    __shared__ float wp_lds[H], bp_lds[H];
    __shared__ float pred_lds[2][64];
    __shared__ int sflag;

    const int tid  = threadIdx.x;
    const int wid  = tid >> 6;
    const int lane = tid & 63;
    const int lo   = lane & 15;
    const int quad = lane >> 4;
    const int rh   = wid & 3;
    const int ch   = wid >> 2;
    const int m0   = blockIdx.x * 64;

    if (tid == 0) sflag = 0;
    __syncthreads();
    if (!(fabsf(b2f(((const unsigned short*)WihP)[tid])) <= 0.25f)) sflag = 1;
    __syncthreads();
    const bool f32in = (sflag != 0);

    const float*          encF = (const float*)encP;
    const unsigned short* encB = (const unsigned short*)encP;
    const unsigned short* WhhB = (const unsigned short*)WhhP;
    const float*          WhhF = (const float*)WhhP;

    if (tid < H) {
        wp_lds[tid] = f32in ? ((const float*)wprojP)[tid] : b2f(((const unsigned short*)wprojP)[tid]);
        bp_lds[tid] = f32in ? ((const float*)bprojP)[tid] : b2f(((const unsigned short*)bprojP)[tid]);
        wo_lds[tid] = f32in ? ((const float*)woutP)[tid]  : b2f(((const unsigned short*)woutP)[tid]);
    }
    __syncthreads();

    for (int j = tid; j < TH; j += 512) {
        float su = 0.f, sc = 0.f;
        if (f32in) {
            const float* row = (const float*)WihP + (size_t)j * H;
            for (int k = 0; k < H; ++k) { float w = row[k]; su = fmaf(w, wp_lds[k], su); sc = fmaf(w, bp_lds[k], sc); }
        } else {
            const unsigned short* row = (const unsigned short*)WihP + (size_t)j * H;
            for (int k = 0; k < H; ++k) { float w = b2f(row[k]); su = fmaf(w, wp_lds[k], su); sc = fmaf(w, bp_lds[k], sc); }
        }
        float bih = f32in ? ((const float*)bihP)[j] : b2f(((const unsigned short*)bihP)[j]);
        float bhh = f32in ? ((const float*)bhhP)[j] : b2f(((const unsigned short*)bhhP)[j]);
        u_lds[j] = su;
        c_lds[j] = sc + bih + (j < 512 ? bhh : 0.f);
        if (j >= 512) bhn_lds[j - 512] = bhh;
    }

    for (int i = tid; i < 64 * H; i += 512) {
        int r = i >> 8, col = i & 255;
        float hv = f32in ? encF[(size_t)(m0 + r) * H + col] : b2f(encB[(size_t)(m0 + r) * H + col]);
        Asf[r * LDA + col] = f2b(hv);
    }
    float hold[8][4];
#pragma unroll
    for (int s = 0; s < 8; ++s)
#pragma unroll
        for (int v = 0; v < 4; ++v) {
            int row = m0 + rh * 16 + quad * 4 + v;
            int jj  = ch * 128 + s * 16 + lo;
            hold[s][v] = f32in ? encF[(size_t)row * H + jj] : b2f(encB[(size_t)row * H + jj]);
        }
    const float b0 = f32in ? ((const float*)boutP)[0] : b2f(((const unsigned short*)boutP)[0]);

    float xm[4] = {0.f, 0.f, 0.f, 0.f};
    __syncthreads();

    const int aBase = (rh * 16 + lo) * LDA;
    const int wCol0 = ch * 128 + lo;

#pragma unroll 1
    for (int t = 0; t < PRED; ++t) {
        floatx4 acc[3][8];
#pragma unroll
        for (int g = 0; g < 3; ++g)
#pragma unroll
            for (int s = 0; s < 8; ++s) acc[g][s] = (floatx4){0.f, 0.f, 0.f, 0.f};

        if (f32in) {
#pragma unroll 1
            for (int kk = 0; kk < 8; ++kk) {
                bf16x8 a = *(const bf16x8*)&Asf[aBase + kk * 32 + quad * 8];
#pragma unroll
                for (int g = 0; g < 3; ++g)
#pragma unroll
                    for (int s = 0; s < 8; ++s) {
                        const float* wr = WhhF + (size_t)(g * 256 + wCol0 + s * 16) * H + kk * 32 + quad * 8;
                        float4 w0 = *(const float4*)wr;
                        float4 w1 = *(const float4*)(wr + 4);
                        bf16x8 b;
                        b[0] = (short)f2b(w0.x); b[1] = (short)f2b(w0.y);
                        b[2] = (short)f2b(w0.z); b[3] = (short)f2b(w0.w);
                        b[4] = (short)f2b(w1.x); b[5] = (short)f2b(w1.y);
                        b[6] = (short)f2b(w1.z); b[7] = (short)f2b(w1.w);
                        acc[g][s] = __builtin_amdgcn_mfma_f32_16x16x32_bf16(a, b, acc[g][s], 0, 0, 0);
                    }
            }
        } else {
#pragma unroll 1
            for (int kk = 0; kk < 8; ++kk) {
                bf16x8 a = *(const bf16x8*)&Asf[aBase + kk * 32 + quad * 8];
#pragma unroll
                for (int g = 0; g < 3; ++g)
#pragma unroll
                    for (int s = 0; s < 8; ++s) {
                        bf16x8 b = *(const bf16x8*)(WhhB + (size_t)(g * 256 + wCol0 + s * 16) * H + kk * 32 + quad * 8);
                        acc[g][s] = __builtin_amdgcn_mfma_f32_16x16x32_bf16(a, b, acc[g][s], 0, 0, 0);
                    }
            }
        }
        __syncthreads();

        float pp[4] = {0.f, 0.f, 0.f, 0.f};
#pragma unroll
        for (int s = 0; s < 8; ++s) {
            const int jj = ch * 128 + s * 16 + lo;
            const float urr = u_lds[jj], uzz = u_lds[256 + jj], unn = u_lds[512 + jj];
            const float crr = c_lds[jj], czz = c_lds[256 + jj], cnn = c_lds[512 + jj];
            const float bhn = bhn_lds[jj], wovv = wo_lds[jj];
#pragma unroll
            for (int v = 0; v < 4; ++v) {
                const float xv = xm[v];
                float r  = fsig(fmaf(xv, urr, crr) + acc[0][s][v]);
                float z  = fsig(fmaf(xv, uzz, czz) + acc[1][s][v]);
                float n  = ftanh(fmaf(xv, unn, cnn) + r * (acc[2][s][v] + bhn));
                float hn = fmaf(z, hold[s][v] - n, n);
                hold[s][v] = hn;
                Asf[(rh * 16 + quad * 4 + v) * LDA + jj] = f2b(hn);
                pp[v] = fmaf(hn, wovv, pp[v]);
            }
        }
#pragma unroll
        for (int v = 0; v < 4; ++v) {
            float pv = pp[v];
            pv += __shfl_xor(pv, 1, 64);
            pv += __shfl_xor(pv, 2, 64);
            pv += __shfl_xor(pv, 4, 64);
            pv += __shfl_xor(pv, 8, 64);
            if (lo == 0) pred_lds[ch][rh * 16 + quad * 4 + v] = pv;
        }
        __syncthreads();

#pragma unroll
        for (int v = 0; v < 4; ++v) {
            const int ml = rh * 16 + quad * 4 + v;
            xm[v] = b0 + pred_lds[0][ml] + pred_lds[1][ml];
        }
        if (tid < 64) {
            float pr = b0 + pred_lds[0][tid] + pred_lds[1][tid];
            if (f32in) ((float*)outP)[(size_t)(m0 + tid) * PRED + t] = pr;
            else ((unsigned short*)outP)[(size_t)(m0 + tid) * PRED + t] = f2b(pr);
        }
    }
}

extern "C" void kernel_launch(void* const* d_in, const int* in_sizes, int n_in,
                              void* d_out, int out_size, void* d_ws, size_t ws_size,
                              hipStream_t stream) {
    if (ws_size >= (size_t)WS_NEEDED) {
        char* ws = (char*)d_ws;
        unsigned short* Wp = (unsigned short*)ws;            // 393216 B
        float* u   = (float*)(ws + 393216);                  // 3072 B
        float* c   = (float*)(ws + 396288);                  // 3072 B
        float* bhn = (float*)(ws + 399360);                  // 1024 B
        float* wo  = (float*)(ws + 400384);                  // 1024 B
        float* b0  = (float*)(ws + 401408);                  // 1024 B
        unsigned short* wf = (unsigned short*)(ws + 402432); // 8192 B
        prep_proj<<<TH, 64, 0, stream>>>(d_in[3], d_in[1], d_in[2], d_in[4], d_in[6],
                                         d_in[7], d_in[8], u, c, bhn, wo, b0);
        prep_swz2<<<96, 256, 0, stream>>>(d_in[5], Wp);
        prep_wof<<<16, 256, 0, stream>>>(wo, wf);
        decode_wr3<<<NS / 32, 512, 0, stream>>>(d_in[0], d_in[3], Wp, wf, u, c, bhn, b0, d_out);
    } else {
        decode_all<<<NS / 64, 512, 0, stream>>>(d_in[0], d_in[1], d_in[2], d_in[3],
                                                d_in[4], d_in[5], d_in[6], d_in[7],
                                                d_in[8], d_out);
    }
}

// Round 15
// 296.068 us; speedup vs baseline: 2.1747x; 1.1299x over previous
//
#include <hip/hip_runtime.h>
#include <hip/hip_bf16.h>

#define NS 16384   // batch
#define H 256      // hidden
#define TH 768     // 3H
#define PRED 24    // decode steps
#define LDA 272    // LDS h-tile row stride (shorts); R3-R14-verified
#define WS_NEEDED (425984)

typedef short bf16x8 __attribute__((ext_vector_type(8)));
typedef float floatx4 __attribute__((ext_vector_type(4)));

__device__ __forceinline__ float b2f(unsigned short u) {
    return __uint_as_float(((unsigned int)u) << 16);
}
__device__ __forceinline__ unsigned short f2b(float f) {   // RTN-even bf16
    unsigned int u = __float_as_uint(f);
    return (unsigned short)((u + 0x7FFFu + ((u >> 16) & 1u)) >> 16);
}
__device__ __forceinline__ float fsig(float v) {
    return __builtin_amdgcn_rcpf(1.0f + __expf(-v));
}
__device__ __forceinline__ float ftanh(float v) {
    return 1.0f - 2.0f * __builtin_amdgcn_rcpf(1.0f + __expf(2.0f * v));
}

// ================= prep 1: rank-1 input-proj collapse + small vectors =================
__global__ void prep_proj(const void* __restrict__ WihP, const void* __restrict__ wprojP,
                          const void* __restrict__ bprojP, const void* __restrict__ bihP,
                          const void* __restrict__ bhhP, const void* __restrict__ woutP,
                          const void* __restrict__ boutP,
                          float* __restrict__ u, float* __restrict__ c,
                          float* __restrict__ bhn, float* __restrict__ wo,
                          float* __restrict__ b0) {
    const int j = blockIdx.x;        // 768
    const int lane = threadIdx.x;    // 64
    unsigned long long bm = __ballot(!(fabsf(b2f(((const unsigned short*)WihP)[lane])) <= 0.25f));
    const bool f32in = (bm != 0ull);

    float su = 0.f, sc = 0.f;
    if (f32in) {
        const float* row = (const float*)WihP + (size_t)j * H;
        const float* wp = (const float*)wprojP;
        const float* bp = (const float*)bprojP;
        for (int k = lane; k < H; k += 64) {
            float w = row[k];
            su = fmaf(w, wp[k], su); sc = fmaf(w, bp[k], sc);
        }
    } else {
        const unsigned short* row = (const unsigned short*)WihP + (size_t)j * H;
        const unsigned short* wp = (const unsigned short*)wprojP;
        const unsigned short* bp = (const unsigned short*)bprojP;
        for (int k = lane; k < H; k += 64) {
            float w = b2f(row[k]);
            su = fmaf(w, b2f(wp[k]), su); sc = fmaf(w, b2f(bp[k]), sc);
        }
    }
    for (int m = 32; m; m >>= 1) { su += __shfl_xor(su, m, 64); sc += __shfl_xor(sc, m, 64); }

    if (lane == 0) {
        float bih = f32in ? ((const float*)bihP)[j] : b2f(((const unsigned short*)bihP)[j]);
        float bhh = f32in ? ((const float*)bhhP)[j] : b2f(((const unsigned short*)bhhP)[j]);
        u[j] = su;
        c[j] = sc + bih + (j < 512 ? bhh : 0.f);
        if (j >= 512) bhn[j - 512] = bhh;
    }
    if (j < H && lane == 1)
        wo[j] = f32in ? ((const float*)woutP)[j] : b2f(((const unsigned short*)woutP)[j]);
    if (j == 0 && lane == 2)
        b0[0] = f32in ? ((const float*)boutP)[0] : b2f(((const unsigned short*)boutP)[0]);
}

// ======== prep 2: swizzle W_hh into MFMA-frag-contiguous bf16, 8-wave map (R9-R14) ======
// frag fi = ((w*8 + kk)*3 + g)*2 + s ; within frag: lane*8 shorts.
__global__ void prep_swz2(const void* __restrict__ WhhP, unsigned short* __restrict__ Wp) {
    const int cidx = blockIdx.x * 256 + threadIdx.x;   // 24576 chunks of 8 shorts
    unsigned long long bm = __ballot(!(fabsf(b2f(((const unsigned short*)WhhP)[threadIdx.x & 63])) <= 0.25f));
    const bool f32in = (bm != 0ull);

    const int lane = cidx & 63;
    const int fi   = cidx >> 6;         // 384 frags
    const int s    = fi & 1;
    const int g    = (fi >> 1) % 3;
    const int kk   = ((fi >> 1) / 3) & 7;
    const int w    = (fi >> 1) / 24;
    const size_t src = (size_t)(g * 256 + s * 128 + w * 16 + (lane & 15)) * H
                     + kk * 32 + (lane >> 4) * 8;
    unsigned short* dst = Wp + (size_t)cidx * 8;
    if (f32in) {
        const float* sp = (const float*)WhhP + src;
#pragma unroll
        for (int e = 0; e < 8; ++e) dst[e] = f2b(sp[e]);
    } else {
        const unsigned short* sp = (const unsigned short*)WhhP + src;
#pragma unroll
        for (int e = 0; e < 8; ++e) dst[e] = sp[e];
    }
}

// ====== fused 24-step decode: R11 residency + row-half software pipeline ======
// 512 blocks x 512 thr (8 waves), 32 rows, 1 block/CU, 2 rounds.  Tile A = rows 0-15,
// tile B = rows 16-31, phase-shifted half a step:
//   phase1: finalize(B,t-1) + epi(A,t) + K(B,t);  barrier;
//   phase2: finalize(A,t)   + epi(B,t) + K(A,t+1); barrier.
// Every phase mixes trans/VALU (epi) with MFMA/LDS (K) in one instruction stream ->
// pipe overlap within each wave (what R9 wanted without the W-traffic cost).
// All math / col-map / W layout / pred reduction identical to R11 (best measured).
__global__ __launch_bounds__(512, 2)
void decode_pipe(const void* __restrict__ encP, const void* __restrict__ WihP,
                 const unsigned short* __restrict__ Wp,
                 const float* __restrict__ u, const float* __restrict__ c,
                 const float* __restrict__ bhnA, const float* __restrict__ woA,
                 const float* __restrict__ b0A, void* __restrict__ outP) {
    __shared__ __align__(16) unsigned short As[32 * LDA];     // 17.4 KB h tile (in-place)
    __shared__ __align__(16) unsigned short Wl[8][6144];      // 96 KB kk6-7 W, wave-private
    __shared__ float pred_part[8][32];
    __shared__ float pred_fin[32];
    __shared__ float pred_out[32][PRED];                      // 3 KB
    __shared__ int sflag;

    const int tid  = threadIdx.x;
    const int w    = tid >> 6;     // 0..7
    const int lane = tid & 63;
    const int lo   = lane & 15;
    const int quad = lane >> 4;
    const int m0   = blockIdx.x * 32;

    if (tid == 0) sflag = 0;
    __syncthreads();
    if (!(fabsf(b2f(((const unsigned short*)WihP)[tid])) <= 0.25f)) sflag = 1;
    __syncthreads();
    const bool f32in = (sflag != 0);

    const float*          encF = (const float*)encP;
    const unsigned short* encB = (const unsigned short*)encP;

    // stage h0 tile (bf16)
    for (int i = tid; i < 32 * H; i += 512) {
        int r = i >> 8, col = i & 255;
        float hv = f32in ? encF[(size_t)(m0 + r) * H + col] : b2f(encB[(size_t)(m0 + r) * H + col]);
        As[r * LDA + col] = f2b(hv);
    }
    if (tid < 32) pred_fin[tid] = 0.f;   // start token x=0

    // per-lane gate constants, jj(s) = s*128 + 16w + lo (R9/R11-verified)
    float ur[2], uz[2], un[2], cr[2], cz[2], cn[2], bh[2], wov[2];
#pragma unroll
    for (int s = 0; s < 2; ++s) {
        const int jj = s * 128 + w * 16 + lo;
        ur[s] = u[jj];       uz[s] = u[256 + jj];       un[s] = u[512 + jj];
        cr[s] = c[jj];       cz[s] = c[256 + jj];       cn[s] = c[512 + jj];
        bh[s] = bhnA[jj];    wov[s] = woA[jj];
    }
    const float b0 = b0A[0];

    // ---- one-time W residency load (R11-verified): kk0-5 regs, kk6-7 wave-private LDS ----
    const unsigned short* wp = Wp + (size_t)w * 24576 + lane * 8;  // + frag*512
    bf16x8 bW[6][3][2];                                            // 144 regs
#pragma unroll
    for (int kk = 0; kk < 6; ++kk)
#pragma unroll
        for (int g = 0; g < 3; ++g)
#pragma unroll
            for (int s = 0; s < 2; ++s)
                bW[kk][g][s] = *(const bf16x8*)(wp + (size_t)((kk * 3 + g) * 2 + s) * 512);
#pragma unroll
    for (int kk = 6; kk < 8; ++kk)
#pragma unroll
        for (int g = 0; g < 3; ++g)
#pragma unroll
            for (int s = 0; s < 2; ++s) {
                bf16x8 v = *(const bf16x8*)(wp + (size_t)((kk * 3 + g) * 2 + s) * 512);
                *(bf16x8*)&Wl[w][(((kk - 6) * 3 + g) * 2 + s) * 512 + lane * 8] = v;
            }
    __syncthreads();   // h0 + Wl visible

    // K-loop helper (per row-half im): R11-identical math
#define KLOOP(ACC, IM)                                                                    \
    do {                                                                                  \
        _Pragma("unroll")                                                                 \
        for (int g = 0; g < 3; ++g)                                                       \
            _Pragma("unroll")                                                             \
            for (int s = 0; s < 2; ++s) ACC[g][s] = (floatx4){0.f, 0.f, 0.f, 0.f};        \
        _Pragma("unroll")                                                                 \
        for (int kk = 0; kk < 8; ++kk) {                                                  \
            bf16x8 a = *(const bf16x8*)&As[((IM) * 16 + lo) * LDA + kk * 32 + quad * 8];  \
            if (kk < 6) {                                                                 \
                _Pragma("unroll")                                                         \
                for (int g = 0; g < 3; ++g)                                               \
                    _Pragma("unroll")                                                     \
                    for (int s = 0; s < 2; ++s)                                           \
                        ACC[g][s] = __builtin_amdgcn_mfma_f32_16x16x32_bf16(              \
                            a, bW[kk][g][s], ACC[g][s], 0, 0, 0);                         \
            } else {                                                                      \
                _Pragma("unroll")                                                         \
                for (int g = 0; g < 3; ++g)                                               \
                    _Pragma("unroll")                                                     \
                    for (int s = 0; s < 2; ++s) {                                         \
                        bf16x8 b = *(const bf16x8*)&Wl[w][(((kk - 6) * 3 + g) * 2 + s) * 512 + lane * 8]; \
                        ACC[g][s] = __builtin_amdgcn_mfma_f32_16x16x32_bf16(              \
                            a, b, ACC[g][s], 0, 0, 0);                                    \
                    }                                                                     \
            }                                                                             \
        }                                                                                 \
    } while (0)

    // epilogue helper (per row-half im): R11-identical math, in-place As update
#define EPILOG(ACC, IM)                                                                   \
    do {                                                                                  \
        _Pragma("unroll")                                                                 \
        for (int v = 0; v < 4; ++v) {                                                     \
            const int row = (IM) * 16 + quad * 4 + v;                                     \
            const float xv = pred_fin[row];                                               \
            float pv = 0.f;                                                               \
            _Pragma("unroll")                                                             \
            for (int s = 0; s < 2; ++s) {                                                 \
                const int jj = s * 128 + w * 16 + lo;                                     \
                const int hofs = row * LDA + jj;                                          \
                const float hold = b2f(As[hofs]);                                         \
                float r  = fsig(fmaf(xv, ur[s], cr[s]) + ACC[0][s][v]);                   \
                float z  = fsig(fmaf(xv, uz[s], cz[s]) + ACC[1][s][v]);                   \
                float n  = ftanh(fmaf(xv, un[s], cn[s]) + r * (ACC[2][s][v] + bh[s]));    \
                float hn = fmaf(z, hold - n, n);                                          \
                As[hofs] = f2b(hn);                                                       \
                pv = fmaf(hn, wov[s], pv);                                                \
            }                                                                             \
            pv += __shfl_xor(pv, 1, 64);                                                  \
            pv += __shfl_xor(pv, 2, 64);                                                  \
            pv += __shfl_xor(pv, 4, 64);                                                  \
            pv += __shfl_xor(pv, 8, 64);                                                  \
            if (lo == 0) pred_part[w][row] = pv;                                          \
        }                                                                                 \
    } while (0)

    floatx4 accA[3][2], accB[3][2];
    KLOOP(accA, 0);   // preamble: K(A,0) — h(A,0) staged, barrier above

#pragma unroll 1
    for (int t = 0; t < PRED; ++t) {
        // ---- phase 1: finalize(B,t-1) + epi(A,t) + K(B,t) ----
        if (t > 0 && tid >= 16 && tid < 32) {
            float pr = b0;
#pragma unroll
            for (int ww = 0; ww < 8; ++ww) pr += pred_part[ww][tid];
            pred_fin[tid] = pr;
            pred_out[tid][t - 1] = pr;
        }
        EPILOG(accA, 0);
        KLOOP(accB, 1);
        __syncthreads();

        // ---- phase 2: finalize(A,t) + epi(B,t) + K(A,t+1) ----
        if (tid < 16) {
            float pr = b0;
#pragma unroll
            for (int ww = 0; ww < 8; ++ww) pr += pred_part[ww][tid];
            pred_fin[tid] = pr;
            pred_out[tid][t] = pr;
        }
        EPILOG(accB, 1);
        if (t < PRED - 1) KLOOP(accA, 0);
        __syncthreads();
    }

    // ---- postamble: finalize(B, t=23) ----
    if (tid >= 16 && tid < 32) {
        float pr = b0;
#pragma unroll
        for (int ww = 0; ww < 8; ++ww) pr += pred_part[ww][tid];
        pred_out[tid][PRED - 1] = pr;
    }
    __syncthreads();

    // single coalesced output store
    for (int i = tid; i < 32 * PRED; i += 512) {
        int row = i / PRED, tt = i % PRED;
        float pr = pred_out[row][tt];
        if (f32in) ((float*)outP)[(size_t)(m0 + row) * PRED + tt] = pr;
        else ((unsigned short*)outP)[(size_t)(m0 + row) * PRED + tt] = f2b(pr);
    }
#undef KLOOP
#undef EPILOG
}

// ================= fallback (R3, proven): zero-workspace fused decode =================
__global__ __launch_bounds__(512, 2)
void decode_all(const void* __restrict__ encP,   const void* __restrict__ wprojP,
                const void* __restrict__ bprojP, const void* __restrict__ WihP,
                const void* __restrict__ bihP,   const void* __restrict__ WhhP,
                const void* __restrict__ bhhP,   const void* __restrict__ woutP,
                const void* __restrict__ boutP,  void* __restrict__ outP) {
    __shared__ __align__(16) unsigned short Asf[64 * LDA];
    __shared__ float u_lds[TH], c_lds[TH];
    __shared__ float bhn_lds[H], wo_lds[H];
    __shared__ float wp_lds[H], bp_lds[H];
    __shared__ float pred_lds[2][64];
    __shared__ int sflag;

    const int tid  = threadIdx.x;
    const int wid  = tid >> 6;
    const int lane = tid & 63;
    const int lo   = lane & 15;
    const int quad = lane >> 4;
    const int rh   = wid & 3;
    const int ch   = wid >> 2;
    const int m0   = blockIdx.x * 64;

    if (tid == 0) sflag = 0;
    __syncthreads();
    if (!(fabsf(b2f(((const unsigned short*)WihP)[tid])) <= 0.25f)) sflag = 1;
    __syncthreads();
    const bool f32in = (sflag != 0);

    const float*          encF = (const float*)encP;
    const unsigned short* encB = (const unsigned short*)encP;
    const unsigned short* WhhB = (const unsigned short*)WhhP;
    const float*          WhhF = (const float*)WhhP;

    if (tid < H) {
        wp_lds[tid] = f32in ? ((const float*)wprojP)[tid] : b2f(((const unsigned short*)wprojP)[tid]);
        bp_lds[tid] = f32in ? ((const float*)bprojP)[tid] : b2f(((const unsigned short*)bprojP)[tid]);
        wo_lds[tid] = f32in ? ((const float*)woutP)[tid]  : b2f(((const unsigned short*)woutP)[tid]);
    }
    __syncthreads();

    for (int j = tid; j < TH; j += 512) {
        float su = 0.f, sc = 0.f;
        if (f32in) {
            const float* row = (const float*)WihP + (size_t)j * H;
            for (int k = 0; k < H; ++k) { float w = row[k]; su = fmaf(w, wp_lds[k], su); sc = fmaf(w, bp_lds[k], sc); }
        } else {
            const unsigned short* row = (const unsigned short*)WihP + (size_t)j * H;
            for (int k = 0; k < H; ++k) { float w = b2f(row[k]); su = fmaf(w, wp_lds[k], su); sc = fmaf(w, bp_lds[k], sc); }
        }
        float bih = f32in ? ((const float*)bihP)[j] : b2f(((const unsigned short*)bihP)[j]);
        float bhh = f32in ? ((const float*)bhhP)[j] : b2f(((const unsigned short*)bhhP)[j]);
        u_lds[j] = su;
        c_lds[j] = sc + bih + (j < 512 ? bhh : 0.f);
        if (j >= 512) bhn_lds[j - 512] = bhh;
    }

    for (int i = tid; i < 64 * H; i += 512) {
        int r = i >> 8, col = i & 255;
        float hv = f32in ? encF[(size_t)(m0 + r) * H + col] : b2f(encB[(size_t)(m0 + r) * H + col]);
        Asf[r * LDA + col] = f2b(hv);
    }
    float hold[8][4];
#pragma unroll
    for (int s = 0; s < 8; ++s)
#pragma unroll
        for (int v = 0; v < 4; ++v) {
            int row = m0 + rh * 16 + quad * 4 + v;
            int jj  = ch * 128 + s * 16 + lo;
            hold[s][v] = f32in ? encF[(size_t)row * H + jj] : b2f(encB[(size_t)row * H + jj]);
        }
    const float b0 = f32in ? ((const float*)boutP)[0] : b2f(((const unsigned short*)boutP)[0]);

    float xm[4] = {0.f, 0.f, 0.f, 0.f};
    __syncthreads();

    const int aBase = (rh * 16 + lo) * LDA;
    const int wCol0 = ch * 128 + lo;

#pragma unroll 1
    for (int t = 0; t < PRED; ++t) {
        floatx4 acc[3][8];
#pragma unroll
        for (int g = 0; g < 3; ++g)
#pragma unroll
            for (int s = 0; s < 8; ++s) acc[g][s] = (floatx4){0.f, 0.f, 0.f, 0.f};

        if (f32in) {
#pragma unroll 1
            for (int kk = 0; kk < 8; ++kk) {
                bf16x8 a = *(const bf16x8*)&Asf[aBase + kk * 32 + quad * 8];
#pragma unroll
                for (int g = 0; g < 3; ++g)
#pragma unroll
                    for (int s = 0; s < 8; ++s) {
                        const float* wr = WhhF + (size_t)(g * 256 + wCol0 + s * 16) * H + kk * 32 + quad * 8;
                        float4 w0 = *(const float4*)wr;
                        float4 w1 = *(const float4*)(wr + 4);
                        bf16x8 b;
                        b[0] = (short)f2b(w0.x); b[1] = (short)f2b(w0.y);
                        b[2] = (short)f2b(w0.z); b[3] = (short)f2b(w0.w);
                        b[4] = (short)f2b(w1.x); b[5] = (short)f2b(w1.y);
                        b[6] = (short)f2b(w1.z); b[7] = (short)f2b(w1.w);
                        acc[g][s] = __builtin_amdgcn_mfma_f32_16x16x32_bf16(a, b, acc[g][s], 0, 0, 0);
                    }
            }
        } else {
#pragma unroll 1
            for (int kk = 0; kk < 8; ++kk) {
                bf16x8 a = *(const bf16x8*)&Asf[aBase + kk * 32 + quad * 8];
#pragma unroll
                for (int g = 0; g < 3; ++g)
#pragma unroll
                    for (int s = 0; s < 8; ++s) {
                        bf16x8 b = *(const bf16x8*)(WhhB + (size_t)(g * 256 + wCol0 + s * 16) * H + kk * 32 + quad * 8);
                        acc[g][s] = __builtin_amdgcn_mfma_f32_16x16x32_bf16(a, b, acc[g][s], 0, 0, 0);
                    }
            }
        }
        __syncthreads();

        float pp[4] = {0.f, 0.f, 0.f, 0.f};
#pragma unroll
        for (int s = 0; s < 8; ++s) {
            const int jj = ch * 128 + s * 16 + lo;
            const float urr = u_lds[jj], uzz = u_lds[256 + jj], unn = u_lds[512 + jj];
            const float crr = c_lds[jj], czz = c_lds[256 + jj], cnn = c_lds[512 + jj];
            const float bhn = bhn_lds[jj], wovv = wo_lds[jj];
#pragma unroll
            for (int v = 0; v < 4; ++v) {
                const float xv = xm[v];
                float r  = fsig(fmaf(xv, urr, crr) + acc[0][s][v]);
                float z  = fsig(fmaf(xv, uzz, czz) + acc[1][s][v]);
                float n  = ftanh(fmaf(xv, unn, cnn) + r * (acc[2][s][v] + bhn));
                float hn = fmaf(z, hold[s][v] - n, n);
                hold[s][v] = hn;
                Asf[(rh * 16 + quad * 4 + v) * LDA + jj] = f2b(hn);
                pp[v] = fmaf(hn, wovv, pp[v]);
            }
        }
#pragma unroll
        for (int v = 0; v < 4; ++v) {
            float pv = pp[v];
            pv += __shfl_xor(pv, 1, 64);
            pv += __shfl_xor(pv, 2, 64);
            pv += __shfl_xor(pv, 4, 64);
            pv += __shfl_xor(pv, 8, 64);
            if (lo == 0) pred_lds[ch][rh * 16 + quad * 4 + v] = pv;
        }
        __syncthreads();

#pragma unroll
        for (int v = 0; v < 4; ++v) {
            const int ml = rh * 16 + quad * 4 + v;
            xm[v] = b0 + pred_lds[0][ml] + pred_lds[1][ml];
        }
        if (tid < 64) {
            float pr = b0 + pred_lds[0][tid] + pred_lds[1][tid];
            if (f32in) ((float*)outP)[(size_t)(m0 + tid) * PRED + t] = pr;
            else ((unsigned short*)outP)[(size_t)(m0 + tid) * PRED + t] = f2b(pr);
        }
    }
}

extern "C" void kernel_launch(void* const* d_in, const int* in_sizes, int n_in,
                              void* d_out, int out_size, void* d_ws, size_t ws_size,
                              hipStream_t stream) {
    if (ws_size >= (size_t)WS_NEEDED) {
        char* ws = (char*)d_ws;
        unsigned short* Wp = (unsigned short*)ws;          // 393216 B
        float* u   = (float*)(ws + 393216);                // 3072 B
        float* c   = (float*)(ws + 396288);                // 3072 B
        float* bhn = (float*)(ws + 399360);                // 1024 B
        float* wo  = (float*)(ws + 400384);                // 1024 B
        float* b0  = (float*)(ws + 401408);                // 4 B
        prep_proj<<<TH, 64, 0, stream>>>(d_in[3], d_in[1], d_in[2], d_in[4], d_in[6],
                                         d_in[7], d_in[8], u, c, bhn, wo, b0);
        prep_swz2<<<96, 256, 0, stream>>>(d_in[5], Wp);
        decode_pipe<<<NS / 32, 512, 0, stream>>>(d_in[0], d_in[3], Wp, u, c, bhn, wo, b0, d_out);
    } else {
        decode_all<<<NS / 64, 512, 0, stream>>>(d_in[0], d_in[1], d_in[2], d_in[3],
                                                d_in[4], d_in[5], d_in[6], d_in[7],
                                                d_in[8], d_out);
    }
}

// Round 17
// 277.284 us; speedup vs baseline: 2.3220x; 1.0677x over previous
//
#include <hip/hip_runtime.h>
#include <hip/hip_bf16.h>

#define NS 16384   // batch
#define H 256      // hidden
#define TH 768     // 3H
#define PRED 24    // decode steps
#define LDA 272    // fallback kernel stride (R3-proven)
#define LDB 264    // decode_pipe stride: 132 dwords % 32 = 4 -> 2-way banks (free, m136)
#define WS_NEEDED (425984)

typedef short bf16x8 __attribute__((ext_vector_type(8)));
typedef float floatx4 __attribute__((ext_vector_type(4)));

__device__ __forceinline__ float b2f(unsigned short u) {
    return __uint_as_float(((unsigned int)u) << 16);
}
__device__ __forceinline__ unsigned short f2b(float f) {   // RTN-even bf16
    unsigned int u = __float_as_uint(f);
    return (unsigned short)((u + 0x7FFFu + ((u >> 16) & 1u)) >> 16);
}
__device__ __forceinline__ float fsig(float v) {
    return __builtin_amdgcn_rcpf(1.0f + __expf(-v));
}
__device__ __forceinline__ float ftanh(float v) {
    return 1.0f - 2.0f * __builtin_amdgcn_rcpf(1.0f + __expf(2.0f * v));
}
// DPP lane-shuffle helper — ctrl must be an ICE, so it is a template parameter.
template <int CTRL>
__device__ __forceinline__ float dpp_f(float x) {
    return __uint_as_float((unsigned)__builtin_amdgcn_mov_dpp(
        (int)__float_as_uint(x), CTRL, 0xF, 0xF, true));
}
// sum over each 16-lane DPP row (our lo-groups): pure VALU, zero LDS-port traffic
__device__ __forceinline__ float red16(float pv) {
    pv += dpp_f<0xB1>(pv);    // quad_perm [1,0,3,2]  = lane^1
    pv += dpp_f<0x4E>(pv);    // quad_perm [2,3,0,1]  = lane^2
    pv += dpp_f<0x141>(pv);   // row_half_mirror      -> adds quad^1 sum
    pv += dpp_f<0x140>(pv);   // row_mirror           -> adds quads^2,^3
    return pv;                // all 16 lanes hold the row sum
}

// ================= prep 1: rank-1 input-proj collapse + small vectors =================
__global__ void prep_proj(const void* __restrict__ WihP, const void* __restrict__ wprojP,
                          const void* __restrict__ bprojP, const void* __restrict__ bihP,
                          const void* __restrict__ bhhP, const void* __restrict__ woutP,
                          const void* __restrict__ boutP,
                          float* __restrict__ u, float* __restrict__ c,
                          float* __restrict__ bhn, float* __restrict__ wo,
                          float* __restrict__ b0) {
    const int j = blockIdx.x;        // 768
    const int lane = threadIdx.x;    // 64
    unsigned long long bm = __ballot(!(fabsf(b2f(((const unsigned short*)WihP)[lane])) <= 0.25f));
    const bool f32in = (bm != 0ull);

    float su = 0.f, sc = 0.f;
    if (f32in) {
        const float* row = (const float*)WihP + (size_t)j * H;
        const float* wp = (const float*)wprojP;
        const float* bp = (const float*)bprojP;
        for (int k = lane; k < H; k += 64) {
            float w = row[k];
            su = fmaf(w, wp[k], su); sc = fmaf(w, bp[k], sc);
        }
    } else {
        const unsigned short* row = (const unsigned short*)WihP + (size_t)j * H;
        const unsigned short* wp = (const unsigned short*)wprojP;
        const unsigned short* bp = (const unsigned short*)bprojP;
        for (int k = lane; k < H; k += 64) {
            float w = b2f(row[k]);
            su = fmaf(w, b2f(wp[k]), su); sc = fmaf(w, b2f(bp[k]), sc);
        }
    }
    for (int m = 32; m; m >>= 1) { su += __shfl_xor(su, m, 64); sc += __shfl_xor(sc, m, 64); }

    if (lane == 0) {
        float bih = f32in ? ((const float*)bihP)[j] : b2f(((const unsigned short*)bihP)[j]);
        float bhh = f32in ? ((const float*)bhhP)[j] : b2f(((const unsigned short*)bhhP)[j]);
        u[j] = su;
        c[j] = sc + bih + (j < 512 ? bhh : 0.f);
        if (j >= 512) bhn[j - 512] = bhh;
    }
    if (j < H && lane == 1)
        wo[j] = f32in ? ((const float*)woutP)[j] : b2f(((const unsigned short*)woutP)[j]);
    if (j == 0 && lane == 2)
        b0[0] = f32in ? ((const float*)boutP)[0] : b2f(((const unsigned short*)boutP)[0]);
}

// ======== prep 2: swizzle W_hh into MFMA-frag-contiguous bf16, 8-wave map (R9-R15) ======
// frag fi = ((w*8 + kk)*3 + g)*2 + s ; within frag: lane*8 shorts.
__global__ void prep_swz2(const void* __restrict__ WhhP, unsigned short* __restrict__ Wp) {
    const int cidx = blockIdx.x * 256 + threadIdx.x;   // 24576 chunks of 8 shorts
    unsigned long long bm = __ballot(!(fabsf(b2f(((const unsigned short*)WhhP)[threadIdx.x & 63])) <= 0.25f));
    const bool f32in = (bm != 0ull);

    const int lane = cidx & 63;
    const int fi   = cidx >> 6;         // 384 frags
    const int s    = fi & 1;
    const int g    = (fi >> 1) % 3;
    const int kk   = ((fi >> 1) / 3) & 7;
    const int w    = (fi >> 1) / 24;
    const size_t src = (size_t)(g * 256 + s * 128 + w * 16 + (lane & 15)) * H
                     + kk * 32 + (lane >> 4) * 8;
    unsigned short* dst = Wp + (size_t)cidx * 8;
    if (f32in) {
        const float* sp = (const float*)WhhP + src;
#pragma unroll
        for (int e = 0; e < 8; ++e) dst[e] = f2b(sp[e]);
    } else {
        const unsigned short* sp = (const unsigned short*)WhhP + src;
#pragma unroll
        for (int e = 0; e < 8; ++e) dst[e] = sp[e];
    }
}

// ====== fused 24-step decode: R15 pipeline + DPP pred-reduction + LDB=264 ======
// 512 blocks x 512 thr (8 waves), 32 rows, 1 block/CU, 2 rounds.  Tile A = rows 0-15,
// tile B = rows 16-31, phase-shifted half a step (R15-verified). Changes vs R15:
//  (1) pred reduction over 16 lanes via DPP butterfly (VALU) -> 16 ds-ops/wave/phase
//      removed from the LDS port; (2) h-tile stride 272->264 (2-way banks, free).
__global__ __launch_bounds__(512, 2)
void decode_pipe(const void* __restrict__ encP, const void* __restrict__ WihP,
                 const unsigned short* __restrict__ Wp,
                 const float* __restrict__ u, const float* __restrict__ c,
                 const float* __restrict__ bhnA, const float* __restrict__ woA,
                 const float* __restrict__ b0A, void* __restrict__ outP) {
    __shared__ __align__(16) unsigned short As[32 * LDB];     // 16.9 KB h tile (in-place)
    __shared__ __align__(16) unsigned short Wl[8][6144];      // 96 KB kk6-7 W, wave-private
    __shared__ float pred_part[8][32];
    __shared__ float pred_fin[32];
    __shared__ float pred_out[32][PRED];                      // 3 KB
    __shared__ int sflag;

    const int tid  = threadIdx.x;
    const int w    = tid >> 6;     // 0..7
    const int lane = tid & 63;
    const int lo   = lane & 15;
    const int quad = lane >> 4;
    const int m0   = blockIdx.x * 32;

    if (tid == 0) sflag = 0;
    __syncthreads();
    if (!(fabsf(b2f(((const unsigned short*)WihP)[tid])) <= 0.25f)) sflag = 1;
    __syncthreads();
    const bool f32in = (sflag != 0);

    const float*          encF = (const float*)encP;
    const unsigned short* encB = (const unsigned short*)encP;

    // stage h0 tile (bf16)
    for (int i = tid; i < 32 * H; i += 512) {
        int r = i >> 8, col = i & 255;
        float hv = f32in ? encF[(size_t)(m0 + r) * H + col] : b2f(encB[(size_t)(m0 + r) * H + col]);
        As[r * LDB + col] = f2b(hv);
    }
    if (tid < 32) pred_fin[tid] = 0.f;   // start token x=0

    // per-lane gate constants, jj(s) = s*128 + 16w + lo (R9-R15-verified)
    float ur[2], uz[2], un[2], cr[2], cz[2], cn[2], bh[2], wov[2];
#pragma unroll
    for (int s = 0; s < 2; ++s) {
        const int jj = s * 128 + w * 16 + lo;
        ur[s] = u[jj];       uz[s] = u[256 + jj];       un[s] = u[512 + jj];
        cr[s] = c[jj];       cz[s] = c[256 + jj];       cn[s] = c[512 + jj];
        bh[s] = bhnA[jj];    wov[s] = woA[jj];
    }
    const float b0 = b0A[0];

    // ---- one-time W residency load (R11-verified): kk0-5 regs, kk6-7 wave-private LDS ----
    const unsigned short* wp = Wp + (size_t)w * 24576 + lane * 8;  // + frag*512
    bf16x8 bW[6][3][2];                                            // 144 regs
#pragma unroll
    for (int kk = 0; kk < 6; ++kk)
#pragma unroll
        for (int g = 0; g < 3; ++g)
#pragma unroll
            for (int s = 0; s < 2; ++s)
                bW[kk][g][s] = *(const bf16x8*)(wp + (size_t)((kk * 3 + g) * 2 + s) * 512);
#pragma unroll
    for (int kk = 6; kk < 8; ++kk)
#pragma unroll
        for (int g = 0; g < 3; ++g)
#pragma unroll
            for (int s = 0; s < 2; ++s) {
                bf16x8 v = *(const bf16x8*)(wp + (size_t)((kk * 3 + g) * 2 + s) * 512);
                *(bf16x8*)&Wl[w][(((kk - 6) * 3 + g) * 2 + s) * 512 + lane * 8] = v;
            }
    __syncthreads();   // h0 + Wl visible

#define KLOOP(ACC, IM)                                                                    \
    do {                                                                                  \
        _Pragma("unroll")                                                                 \
        for (int g = 0; g < 3; ++g)                                                       \
            _Pragma("unroll")                                                             \
            for (int s = 0; s < 2; ++s) ACC[g][s] = (floatx4){0.f, 0.f, 0.f, 0.f};        \
        _Pragma("unroll")                                                                 \
        for (int kk = 0; kk < 8; ++kk) {                                                  \
            bf16x8 a = *(const bf16x8*)&As[((IM) * 16 + lo) * LDB + kk * 32 + quad * 8];  \
            if (kk < 6) {                                                                 \
                _Pragma("unroll")                                                         \
                for (int g = 0; g < 3; ++g)                                               \
                    _Pragma("unroll")                                                     \
                    for (int s = 0; s < 2; ++s)                                           \
                        ACC[g][s] = __builtin_amdgcn_mfma_f32_16x16x32_bf16(              \
                            a, bW[kk][g][s], ACC[g][s], 0, 0, 0);                         \
            } else {                                                                      \
                _Pragma("unroll")                                                         \
                for (int g = 0; g < 3; ++g)                                               \
                    _Pragma("unroll")                                                     \
                    for (int s = 0; s < 2; ++s) {                                         \
                        bf16x8 b = *(const bf16x8*)&Wl[w][(((kk - 6) * 3 + g) * 2 + s) * 512 + lane * 8]; \
                        ACC[g][s] = __builtin_amdgcn_mfma_f32_16x16x32_bf16(              \
                            a, b, ACC[g][s], 0, 0, 0);                                    \
                    }                                                                     \
            }                                                                             \
        }                                                                                 \
    } while (0)

#define EPILOG(ACC, IM)                                                                   \
    do {                                                                                  \
        _Pragma("unroll")                                                                 \
        for (int v = 0; v < 4; ++v) {                                                     \
            const int row = (IM) * 16 + quad * 4 + v;                                     \
            const float xv = pred_fin[row];                                               \
            float pv = 0.f;                                                               \
            _Pragma("unroll")                                                             \
            for (int s = 0; s < 2; ++s) {                                                 \
                const int jj = s * 128 + w * 16 + lo;                                     \
                const int hofs = row * LDB + jj;                                          \
                const float hold = b2f(As[hofs]);                                         \
                float r  = fsig(fmaf(xv, ur[s], cr[s]) + ACC[0][s][v]);                   \
                float z  = fsig(fmaf(xv, uz[s], cz[s]) + ACC[1][s][v]);                   \
                float n  = ftanh(fmaf(xv, un[s], cn[s]) + r * (ACC[2][s][v] + bh[s]));    \
                float hn = fmaf(z, hold - n, n);                                          \
                As[hofs] = f2b(hn);                                                       \
                pv = fmaf(hn, wov[s], pv);                                                \
            }                                                                             \
            pv = red16(pv);                  /* DPP butterfly: VALU-only 16-lane sum */   \
            if (lo == 0) pred_part[w][row] = pv;                                          \
        }                                                                                 \
    } while (0)

    floatx4 accA[3][2], accB[3][2];
    KLOOP(accA, 0);   // preamble: K(A,0) — h(A,0) staged, barrier above

#pragma unroll 1
    for (int t = 0; t < PRED; ++t) {
        // ---- phase 1: finalize(B,t-1) + epi(A,t) + K(B,t) ----
        if (t > 0 && tid >= 16 && tid < 32) {
            float pr = b0;
#pragma unroll
            for (int ww = 0; ww < 8; ++ww) pr += pred_part[ww][tid];
            pred_fin[tid] = pr;
            pred_out[tid][t - 1] = pr;
        }
        EPILOG(accA, 0);
        KLOOP(accB, 1);
        __syncthreads();

        // ---- phase 2: finalize(A,t) + epi(B,t) + K(A,t+1) ----
        if (tid < 16) {
            float pr = b0;
#pragma unroll
            for (int ww = 0; ww < 8; ++ww) pr += pred_part[ww][tid];
            pred_fin[tid] = pr;
            pred_out[tid][t] = pr;
        }
        EPILOG(accB, 1);
        if (t < PRED - 1) KLOOP(accA, 0);
        __syncthreads();
    }

    // ---- postamble: finalize(B, t=23) ----
    if (tid >= 16 && tid < 32) {
        float pr = b0;
#pragma unroll
        for (int ww = 0; ww < 8; ++ww) pr += pred_part[ww][tid];
        pred_out[tid][PRED - 1] = pr;
    }
    __syncthreads();

    // single coalesced output store
    for (int i = tid; i < 32 * PRED; i += 512) {
        int row = i / PRED, tt = i % PRED;
        float pr = pred_out[row][tt];
        if (f32in) ((float*)outP)[(size_t)(m0 + row) * PRED + tt] = pr;
        else ((unsigned short*)outP)[(size_t)(m0 + row) * PRED + tt] = f2b(pr);
    }
#undef KLOOP
#undef EPILOG
}

// ================= fallback (R3, proven): zero-workspace fused decode =================
__global__ __launch_bounds__(512, 2)
void decode_all(const void* __restrict__ encP,   const void* __restrict__ wprojP,
                const void* __restrict__ bprojP, const void* __restrict__ WihP,
                const void* __restrict__ bihP,   const void* __restrict__ WhhP,
                const void* __restrict__ bhhP,   const void* __restrict__ woutP,
                const void* __restrict__ boutP,  void* __restrict__ outP) {
    __shared__ __align__(16) unsigned short Asf[64 * LDA];
    __shared__ float u_lds[TH], c_lds[TH];
    __shared__ float bhn_lds[H], wo_lds[H];
    __shared__ float wp_lds[H], bp_lds[H];
    __shared__ float pred_lds[2][64];
    __shared__ int sflag;

    const int tid  = threadIdx.x;
    const int wid  = tid >> 6;
    const int lane = tid & 63;
    const int lo   = lane & 15;
    const int quad = lane >> 4;
    const int rh   = wid & 3;
    const int ch   = wid >> 2;
    const int m0   = blockIdx.x * 64;

    if (tid == 0) sflag = 0;
    __syncthreads();
    if (!(fabsf(b2f(((const unsigned short*)WihP)[tid])) <= 0.25f)) sflag = 1;
    __syncthreads();
    const bool f32in = (sflag != 0);

    const float*          encF = (const float*)encP;
    const unsigned short* encB = (const unsigned short*)encP;
    const unsigned short* WhhB = (const unsigned short*)WhhP;
    const float*          WhhF = (const float*)WhhP;

    if (tid < H) {
        wp_lds[tid] = f32in ? ((const float*)wprojP)[tid] : b2f(((const unsigned short*)wprojP)[tid]);
        bp_lds[tid] = f32in ? ((const float*)bprojP)[tid] : b2f(((const unsigned short*)bprojP)[tid]);
        wo_lds[tid] = f32in ? ((const float*)woutP)[tid]  : b2f(((const unsigned short*)woutP)[tid]);
    }
    __syncthreads();

    for (int j = tid; j < TH; j += 512) {
        float su = 0.f, sc = 0.f;
        if (f32in) {
            const float* row = (const float*)WihP + (size_t)j * H;
            for (int k = 0; k < H; ++k) { float w = row[k]; su = fmaf(w, wp_lds[k], su); sc = fmaf(w, bp_lds[k], sc); }
        } else {
            const unsigned short* row = (const unsigned short*)WihP + (size_t)j * H;
            for (int k = 0; k < H; ++k) { float w = b2f(row[k]); su = fmaf(w, wp_lds[k], su); sc = fmaf(w, bp_lds[k], sc); }
        }
        float bih = f32in ? ((const float*)bihP)[j] : b2f(((const unsigned short*)bihP)[j]);
        float bhh = f32in ? ((const float*)bhhP)[j] : b2f(((const unsigned short*)bhhP)[j]);
        u_lds[j] = su;
        c_lds[j] = sc + bih + (j < 512 ? bhh : 0.f);
        if (j >= 512) bhn_lds[j - 512] = bhh;
    }

    for (int i = tid; i < 64 * H; i += 512) {
        int r = i >> 8, col = i & 255;
        float hv = f32in ? encF[(size_t)(m0 + r) * H + col] : b2f(encB[(size_t)(m0 + r) * H + col]);
        Asf[r * LDA + col] = f2b(hv);
    }
    float hold[8][4];
#pragma unroll
    for (int s = 0; s < 8; ++s)
#pragma unroll
        for (int v = 0; v < 4; ++v) {
            int row = m0 + rh * 16 + quad * 4 + v;
            int jj  = ch * 128 + s * 16 + lo;
            hold[s][v] = f32in ? encF[(size_t)row * H + jj] : b2f(encB[(size_t)row * H + jj]);
        }
    const float b0 = f32in ? ((const float*)boutP)[0] : b2f(((const unsigned short*)boutP)[0]);

    float xm[4] = {0.f, 0.f, 0.f, 0.f};
    __syncthreads();

    const int aBase = (rh * 16 + lo) * LDA;
    const int wCol0 = ch * 128 + lo;

#pragma unroll 1
    for (int t = 0; t < PRED; ++t) {
        floatx4 acc[3][8];
#pragma unroll
        for (int g = 0; g < 3; ++g)
#pragma unroll
            for (int s = 0; s < 8; ++s) acc[g][s] = (floatx4){0.f, 0.f, 0.f, 0.f};

        if (f32in) {
#pragma unroll 1
            for (int kk = 0; kk < 8; ++kk) {
                bf16x8 a = *(const bf16x8*)&Asf[aBase + kk * 32 + quad * 8];
#pragma unroll
                for (int g = 0; g < 3; ++g)
#pragma unroll
                    for (int s = 0; s < 8; ++s) {
                        const float* wr = WhhF + (size_t)(g * 256 + wCol0 + s * 16) * H + kk * 32 + quad * 8;
                        float4 w0 = *(const float4*)wr;
                        float4 w1 = *(const float4*)(wr + 4);
                        bf16x8 b;
                        b[0] = (short)f2b(w0.x); b[1] = (short)f2b(w0.y);
                        b[2] = (short)f2b(w0.z); b[3] = (short)f2b(w0.w);
                        b[4] = (short)f2b(w1.x); b[5] = (short)f2b(w1.y);
                        b[6] = (short)f2b(w1.z); b[7] = (short)f2b(w1.w);
                        acc[g][s] = __builtin_amdgcn_mfma_f32_16x16x32_bf16(a, b, acc[g][s], 0, 0, 0);
                    }
            }
        } else {
#pragma unroll 1
            for (int kk = 0; kk < 8; ++kk) {
                bf16x8 a = *(const bf16x8*)&Asf[aBase + kk * 32 + quad * 8];
#pragma unroll
                for (int g = 0; g < 3; ++g)
#pragma unroll
                    for (int s = 0; s < 8; ++s) {
                        bf16x8 b = *(const bf16x8*)(WhhB + (size_t)(g * 256 + wCol0 + s * 16) * H + kk * 32 + quad * 8);
                        acc[g][s] = __builtin_amdgcn_mfma_f32_16x16x32_bf16(a, b, acc[g][s], 0, 0, 0);
                    }
            }
        }
        __syncthreads();

        float pp[4] = {0.f, 0.f, 0.f, 0.f};
#pragma unroll
        for (int s = 0; s < 8; ++s) {
            const int jj = ch * 128 + s * 16 + lo;
            const float urr = u_lds[jj], uzz = u_lds[256 + jj], unn = u_lds[512 + jj];
            const float crr = c_lds[jj], czz = c_lds[256 + jj], cnn = c_lds[512 + jj];
            const float bhn = bhn_lds[jj], wovv = wo_lds[jj];
#pragma unroll
            for (int v = 0; v < 4; ++v) {
                const float xv = xm[v];
                float r  = fsig(fmaf(xv, urr, crr) + acc[0][s][v]);
                float z  = fsig(fmaf(xv, uzz, czz) + acc[1][s][v]);
                float n  = ftanh(fmaf(xv, unn, cnn) + r * (acc[2][s][v] + bhn));
                float hn = fmaf(z, hold[s][v] - n, n);
                hold[s][v] = hn;
                Asf[(rh * 16 + quad * 4 + v) * LDA + jj] = f2b(hn);
                pp[v] = fmaf(hn, wovv, pp[v]);
            }
        }
#pragma unroll
        for (int v = 0; v < 4; ++v) {
            float pv = pp[v];
            pv += __shfl_xor(pv, 1, 64);
            pv += __shfl_xor(pv, 2, 64);
            pv += __shfl_xor(pv, 4, 64);
            pv += __shfl_xor(pv, 8, 64);
            if (lo == 0) pred_lds[ch][rh * 16 + quad * 4 + v] = pv;
        }
        __syncthreads();

#pragma unroll
        for (int v = 0; v < 4; ++v) {
            const int ml = rh * 16 + quad * 4 + v;
            xm[v] = b0 + pred_lds[0][ml] + pred_lds[1][ml];
        }
        if (tid < 64) {
            float pr = b0 + pred_lds[0][tid] + pred_lds[1][tid];
            if (f32in) ((float*)outP)[(size_t)(m0 + tid) * PRED + t] = pr;
            else ((unsigned short*)outP)[(size_t)(m0 + tid) * PRED + t] = f2b(pr);
        }
    }
}

extern "C" void kernel_launch(void* const* d_in, const int* in_sizes, int n_in,
                              void* d_out, int out_size, void* d_ws, size_t ws_size,
                              hipStream_t stream) {
    if (ws_size >= (size_t)WS_NEEDED) {
        char* ws = (char*)d_ws;
        unsigned short* Wp = (unsigned short*)ws;          // 393216 B
        float* u   = (float*)(ws + 393216);                // 3072 B
        float* c   = (float*)(ws + 396288);                // 3072 B
        float* bhn = (float*)(ws + 399360);                // 1024 B
        float* wo  = (float*)(ws + 400384);                // 1024 B
        float* b0  = (float*)(ws + 401408);                // 4 B
        prep_proj<<<TH, 64, 0, stream>>>(d_in[3], d_in[1], d_in[2], d_in[4], d_in[6],
                                         d_in[7], d_in[8], u, c, bhn, wo, b0);
        prep_swz2<<<96, 256, 0, stream>>>(d_in[5], Wp);
        decode_pipe<<<NS / 32, 512, 0, stream>>>(d_in[0], d_in[3], Wp, u, c, bhn, wo, b0, d_out);
    } else {
        decode_all<<<NS / 64, 512, 0, stream>>>(d_in[0], d_in[1], d_in[2], d_in[3],
                                                d_in[4], d_in[5], d_in[6], d_in[7],
                                                d_in[8], d_out);
    }
}